// Round 8
// baseline (172.647 us; speedup 1.0000x reference)
//
#include <hip/hip_runtime.h>
#include <cstdint>

// ---------------------------------------------------------------------------
// PointCLIP forward on MI355X. GEMMs in bf16 MFMA (fp32 accum), rest fp32.
// 64x128 tiles (4 waves, 8 MFMA/step) for high block-level TLP on the small
// grids this workload has. Weights converted fp32->bf16 in-GEMM (reg-staged).
// Dims fixed per reference: B=512, V=10, D=1024, C=100, P=4.
// ---------------------------------------------------------------------------

typedef unsigned short u16;
typedef __attribute__((ext_vector_type(8))) short bf8v;   // 8 bf16 (4 VGPR)
typedef __attribute__((ext_vector_type(4))) float f4v;    // 4 f32 acc

__device__ __forceinline__ float4 ld4(const float* p){ return *reinterpret_cast<const float4*>(p); }
__device__ __forceinline__ void st4(float* p, float4 v){ *reinterpret_cast<float4*>(p) = v; }
__device__ __forceinline__ u16 f2bf(float x){            // RNE fp32 -> bf16
  uint32_t u = __float_as_uint(x);
  return (u16)((u + 0x7FFFu + ((u>>16)&1u)) >> 16);
}
__device__ __forceinline__ uint32_t pk(float a, float b){
  return (uint32_t)f2bf(a) | ((uint32_t)f2bf(b)<<16);
}
__device__ __forceinline__ void glds16(const u16* g, u16* l){
  __builtin_amdgcn_global_load_lds(
      (const __attribute__((address_space(1))) unsigned int*)g,
      (__attribute__((address_space(3))) unsigned int*)l, 16, 0, 0);
}

// ---------------- bf16 NT MFMA GEMM, 64x128 tile (B bf16) ------------------
// A: (M,K) bf16 row-major. B: (N,K) bf16 row-major. C fp32 ldc, split-K slab.
// 4 waves; wave w owns 32x64 (2x4 frags). BK=32, XOR slot-swizzle, LDS dbuf.
__global__ __launch_bounds__(256,4)
void gemm_bf16_nt(const u16* __restrict__ A, const u16* __restrict__ B,
                  float* __restrict__ C, int lda, int ldb, int ldc,
                  int kLen, long strideCz)
{
  __shared__ u16 As0[2048], Bs0[4096], As1[2048], Bs1[4096];
  const int tid = threadIdx.x, lane = tid & 63, w = tid >> 6;
  const long bm = (long)blockIdx.y*64, bn = (long)blockIdx.x*128;
  const long kz = (long)blockIdx.z*kLen;
  C += (long)blockIdx.z*strideCz;

  const int srow  = lane>>2;
  const int sslot = (lane&3) ^ ((lane>>3)&3);
  const u16* Ag = A + (bm + w*16 + srow)*(long)lda + kz + sslot*8;
  const u16* Bg = B + (bn + w*32 + srow)*(long)ldb + kz + sslot*8;
  const long b16 = 16L*ldb;
  const int woffA = w*512, woffB = w*1024;

  const int fr = lane & 15;
  const int rslot = ((lane>>4) ^ ((lane>>1)&3))*16;
  const int wr = (w>>1)*32, wc = (w&1)*64;

  const f4v zero = {0.f,0.f,0.f,0.f};
  f4v acc[2][4];
  #pragma unroll
  for (int i=0;i<2;i++)
    #pragma unroll
    for (int j=0;j<4;j++) acc[i][j]=zero;

  auto STAGE = [&](u16* Al, u16* Bl, int kt){
    glds16(Ag + kt,       Al + woffA);
    glds16(Bg + kt,       Bl + woffB);
    glds16(Bg + kt + b16, Bl + woffB + 512);
  };
  auto COMPUTE = [&](const u16* Asb, const u16* Bsb){
    bf8v af[2], bf[4];
    #pragma unroll
    for (int mi=0; mi<2; ++mi)
      af[mi] = *(const bf8v*)((const char*)Asb + (wr+mi*16+fr)*64 + rslot);
    #pragma unroll
    for (int nj=0; nj<4; ++nj)
      bf[nj] = *(const bf8v*)((const char*)Bsb + (wc+nj*16+fr)*64 + rslot);
    #pragma unroll
    for (int mi=0; mi<2; ++mi)
      #pragma unroll
      for (int nj=0; nj<4; ++nj)
        acc[mi][nj] = __builtin_amdgcn_mfma_f32_16x16x32_bf16(af[mi], bf[nj], acc[mi][nj], 0,0,0);
  };

  STAGE(As0, Bs0, 0);
  __syncthreads();
  int kt = 32;
  for (; kt < kLen - 32; kt += 64){
    STAGE(As1, Bs1, kt);
    COMPUTE(As0, Bs0);
    __syncthreads();
    STAGE(As0, Bs0, kt + 32);
    COMPUTE(As1, Bs1);
    __syncthreads();
  }
  STAGE(As1, Bs1, kt);
  COMPUTE(As0, Bs0);
  __syncthreads();
  COMPUTE(As1, Bs1);

  const int orow = (lane>>4)*4;
  #pragma unroll
  for (int mi=0;mi<2;++mi){
    #pragma unroll
    for (int q=0;q<4;++q){
      const long row = bm + wr + mi*16 + orow + q;
      float* Crow = C + row*(long)ldc + bn + wc + fr;
      #pragma unroll
      for (int nj=0;nj<4;++nj) Crow[nj*16] = acc[mi][nj][q];
    }
  }
}

// ------------- bf16(A) x fp32(B) NT MFMA GEMM, 64x128 tile -----------------
// B fp32 in HBM: reg-stage 16 floats/thread, convert in-register, ds_write
// into the XOR-swizzled layout (bank-balanced).
__global__ __launch_bounds__(256,4)
void gemm_bf32b_nt(const u16* __restrict__ A, const float* __restrict__ B,
                   float* __restrict__ C, int lda, int ldb, int ldc,
                   int kLen, long strideCz)
{
  __shared__ u16 As0[2048], Bs0[4096], As1[2048], Bs1[4096];
  const int tid = threadIdx.x, lane = tid & 63, w = tid >> 6;
  const long bm = (long)blockIdx.y*64, bn = (long)blockIdx.x*128;
  const long kz = (long)blockIdx.z*kLen;
  C += (long)blockIdx.z*strideCz;

  // A staging via global_load_lds (bf16): wave w rows [w*16, w*16+16)
  const int srow  = lane>>2;
  const int sslot = (lane&3) ^ ((lane>>3)&3);
  const u16* Ag = A + (bm + w*16 + srow)*(long)lda + kz + sslot*8;
  const int woffA = w*512;

  // B reg staging: thread t -> row rB=t>>1 (0..127), slot pair sp=(t&1)*2
  const int rB = tid>>1, sp = (tid&1)<<1, mB = (rB>>1)&3;
  const float* Bg = B + (bn + rB)*(long)ldb + kz + sp*8;   // 16 floats
  const int bo0 = rB*32 + ((sp  )^mB)*8;   // u16 index of slot sp
  const int bo1 = rB*32 + ((sp+1)^mB)*8;   // u16 index of slot sp+1

  const int fr = lane & 15;
  const int rslot = ((lane>>4) ^ ((lane>>1)&3))*16;
  const int wr = (w>>1)*32, wc = (w&1)*64;

  const f4v zero = {0.f,0.f,0.f,0.f};
  f4v acc[2][4];
  #pragma unroll
  for (int i=0;i<2;i++)
    #pragma unroll
    for (int j=0;j<4;j++) acc[i][j]=zero;

  float4 br0[4], br1[4];
  auto LOADB = [&](float4* r4, int kt){
    r4[0]=ld4(Bg+kt); r4[1]=ld4(Bg+kt+4); r4[2]=ld4(Bg+kt+8); r4[3]=ld4(Bg+kt+12);
  };
  auto WRITEB = [&](u16* Bsb, const float4* r4){
    uint4 o0, o1;
    o0.x=pk(r4[0].x,r4[0].y); o0.y=pk(r4[0].z,r4[0].w);
    o0.z=pk(r4[1].x,r4[1].y); o0.w=pk(r4[1].z,r4[1].w);
    o1.x=pk(r4[2].x,r4[2].y); o1.y=pk(r4[2].z,r4[2].w);
    o1.z=pk(r4[3].x,r4[3].y); o1.w=pk(r4[3].z,r4[3].w);
    *reinterpret_cast<uint4*>(&Bsb[bo0]) = o0;
    *reinterpret_cast<uint4*>(&Bsb[bo1]) = o1;
  };
  auto GLA = [&](u16* Al, int kt){ glds16(Ag + kt, Al + woffA); };
  auto COMPUTE = [&](const u16* Asb, const u16* Bsb){
    bf8v af[2], bf[4];
    #pragma unroll
    for (int mi=0; mi<2; ++mi)
      af[mi] = *(const bf8v*)((const char*)Asb + (wr+mi*16+fr)*64 + rslot);
    #pragma unroll
    for (int nj=0; nj<4; ++nj)
      bf[nj] = *(const bf8v*)((const char*)Bsb + (wc+nj*16+fr)*64 + rslot);
    #pragma unroll
    for (int mi=0; mi<2; ++mi)
      #pragma unroll
      for (int nj=0; nj<4; ++nj)
        acc[mi][nj] = __builtin_amdgcn_mfma_f32_16x16x32_bf16(af[mi], bf[nj], acc[mi][nj], 0,0,0);
  };

  LOADB(br0, 0); GLA(As0, 0);
  WRITEB(Bs0, br0);               // waits only on br0 loads
  __syncthreads();
  int kt = 32;
  for (; kt < kLen - 32; kt += 64){
    LOADB(br1, kt); GLA(As1, kt);
    COMPUTE(As0, Bs0);            // covers br1/A latency
    WRITEB(Bs1, br1);
    __syncthreads();
    LOADB(br0, kt+32); GLA(As0, kt+32);
    COMPUTE(As1, Bs1);
    WRITEB(Bs0, br0);
    __syncthreads();
  }
  LOADB(br1, kt); GLA(As1, kt);
  COMPUTE(As0, Bs0);
  WRITEB(Bs1, br1);
  __syncthreads();
  COMPUTE(As1, Bs1);

  const int orow = (lane>>4)*4;
  #pragma unroll
  for (int mi=0;mi<2;++mi){
    #pragma unroll
    for (int q=0;q<4;++q){
      const long row = bm + wr + mi*16 + orow + q;
      float* Crow = C + row*(long)ldc + bn + wc + fr;
      #pragma unroll
      for (int nj=0;nj<4;++nj) Crow[nj*16] = acc[mi][nj][q];
    }
  }
}

// --------------------- split-K reduce variants -----------------------------
__global__ __launch_bounds__(256)
void reduce_f32(const float* __restrict__ P, int S, int MN,
                const float* __restrict__ bias, float* __restrict__ out)
{
  const long i = ((long)blockIdx.x*256 + threadIdx.x)*4;
  float4 s = ld4(&P[i]);
  for (int z=1; z<S; ++z){
    const float4 v = ld4(&P[(long)z*MN + i]);
    s.x+=v.x; s.y+=v.y; s.z+=v.z; s.w+=v.w;
  }
  const float4 b = ld4(&bias[(int)(i & 1023)]);
  s.x+=b.x; s.y+=b.y; s.z+=b.z; s.w+=b.w;
  st4(&out[i], s);
}

__global__ __launch_bounds__(256)
void reduce_bf16(const float* __restrict__ P, int S, int MN,
                 const float* __restrict__ bias, u16* __restrict__ out)
{
  const long i = ((long)blockIdx.x*256 + threadIdx.x)*4;
  float4 s = ld4(&P[i]);
  for (int z=1; z<S; ++z){
    const float4 v = ld4(&P[(long)z*MN + i]);
    s.x+=v.x; s.y+=v.y; s.z+=v.z; s.w+=v.w;
  }
  const float4 b = ld4(&bias[(int)(i & 1023)]);
  s.x = fmaxf(s.x+b.x,0.f); s.y = fmaxf(s.y+b.y,0.f);
  s.z = fmaxf(s.z+b.z,0.f); s.w = fmaxf(s.w+b.w,0.f);
  uint2 o; o.x = pk(s.x,s.y); o.y = pk(s.z,s.w);
  *reinterpret_cast<uint2*>(&out[i]) = o;
}

// --------------- column stats: multi-stage tree, NO atomics ----------------
__global__ __launch_bounds__(256)
void colstats_p1(const float* __restrict__ X, int rpb, const float* __restrict__ fr,
                 float* __restrict__ part)
{
  const int c = threadIdx.x*4;
  const long r0 = (long)blockIdx.x*rpb;
  float4 s = make_float4(0,0,0,0), q = make_float4(0,0,0,0);
  for (int rr=0; rr<rpb; ++rr){
    const long r = r0+rr;
    float4 x = ld4(&X[r*1024 + c]);
    if (fr){ const float f = fr[(int)(r%10)]; x.x*=f; x.y*=f; x.z*=f; x.w*=f; }
    s.x+=x.x; s.y+=x.y; s.z+=x.z; s.w+=x.w;
    q.x+=x.x*x.x; q.y+=x.y*x.y; q.z+=x.z*x.z; q.w+=x.w*x.w;
  }
  float* p = part + (long)blockIdx.x*2048;
  st4(&p[c], s);
  st4(&p[1024+c], q);
}

__global__ __launch_bounds__(256)
void colstats_reduce(const float* __restrict__ in, float* __restrict__ out,
                     int nslab, int chunk)
{
  const int idx = blockIdx.x*256 + threadIdx.x;    // 0..2047
  const int s0 = blockIdx.y*chunk;
  const int s1 = min(nslab, s0+chunk);
  float a0=0.f, a1=0.f, a2=0.f, a3=0.f;
  int s = s0;
  for (; s+4 <= s1; s += 4){
    a0 += in[(long)s*2048+idx];
    a1 += in[(long)(s+1)*2048+idx];
    a2 += in[(long)(s+2)*2048+idx];
    a3 += in[(long)(s+3)*2048+idx];
  }
  for (; s < s1; ++s) a0 += in[(long)s*2048+idx];
  out[(long)blockIdx.y*2048 + idx] = (a0+a1)+(a2+a3);
}

// BN apply with inline finalize (same arithmetic as reference BN).
__global__ __launch_bounds__(256)
void bn_apply_bf16(const float* __restrict__ X, const float* __restrict__ fr,
                   const float* __restrict__ stats, float invN,
                   const float* __restrict__ gamma,
                   const float* __restrict__ beta, int relu, u16* __restrict__ out)
{
  const long i = ((long)blockIdx.x*256 + threadIdx.x)*4;
  const int d = (int)(i & 1023);
  const float4 s  = ld4(&stats[d]);
  const float4 qq = ld4(&stats[1024+d]);
  const float4 gm = ld4(&gamma[d]);
  const float4 bt = ld4(&beta[d]);
  float4 sc, sh;
  { const float m=s.x*invN, v=qq.x*invN-m*m; sc.x=gm.x*rsqrtf(v+1e-5f); sh.x=bt.x-m*sc.x; }
  { const float m=s.y*invN, v=qq.y*invN-m*m; sc.y=gm.y*rsqrtf(v+1e-5f); sh.y=bt.y-m*sc.y; }
  { const float m=s.z*invN, v=qq.z*invN-m*m; sc.z=gm.z*rsqrtf(v+1e-5f); sh.z=bt.z-m*sc.z; }
  { const float m=s.w*invN, v=qq.w*invN-m*m; sc.w=gm.w*rsqrtf(v+1e-5f); sh.w=bt.w-m*sc.w; }
  float4 x = ld4(&X[i]);
  if (fr){ const float f = fr[(int)((i>>10)%10)]; x.x*=f; x.y*=f; x.z*=f; x.w*=f; }
  x.x = x.x*sc.x + sh.x; x.y = x.y*sc.y + sh.y;
  x.z = x.z*sc.z + sh.z; x.w = x.w*sc.w + sh.w;
  if (relu){ x.x=fmaxf(x.x,0.f); x.y=fmaxf(x.y,0.f); x.z=fmaxf(x.z,0.f); x.w=fmaxf(x.w,0.f); }
  uint2 o; o.x = pk(x.x,x.y); o.y = pk(x.z,x.w);
  *reinterpret_cast<uint2*>(&out[i]) = o;
}

__device__ __forceinline__ float blockSum256(float v, float* sh4){
  #pragma unroll
  for (int m=32; m; m>>=1) v += __shfl_xor(v, m, 64);
  const int w = threadIdx.x >> 6;
  if ((threadIdx.x & 63) == 0) sh4[w] = v;
  __syncthreads();
  return sh4[0]+sh4[1]+sh4[2]+sh4[3];
}

// text rows L2-normalized -> bf16; rows [400,512) zero-padded.
__global__ __launch_bounds__(256)
void rownorm_bf16(const float* __restrict__ X, u16* __restrict__ out)
{
  __shared__ float sh4[4];
  const int row = blockIdx.x;
  const int d = threadIdx.x*4;
  if (row >= 400){ *reinterpret_cast<uint2*>(&out[(long)row*1024 + d]) = make_uint2(0,0); return; }
  const long base = (long)row*1024 + d;
  const float4 x = ld4(&X[base]);
  const float ss = x.x*x.x + x.y*x.y + x.z*x.z + x.w*x.w;
  const float rn = rsqrtf(blockSum256(ss, sh4));
  uint2 o; o.x = pk(x.x*rn, x.y*rn); o.y = pk(x.z*rn, x.w*rn);
  *reinterpret_cast<uint2*>(&out[base]) = o;
}

// img = 0.6*relu(y3+bv2) + 0.4*feat; L2-normalize per (b,v) row; bf16 out.
__global__ __launch_bounds__(256)
void mix_norm_bf16(const float* __restrict__ P, const float* __restrict__ feat,
                   const float* __restrict__ bv2, u16* __restrict__ outp)
{
  __shared__ float sh4[4];
  const int m = blockIdx.x;            // 0..5119 = b*10+v
  const int v = m % 10;
  const long base = (long)m*1024;
  const int d = threadIdx.x*4;
  const float4 y  = ld4(&P[base+d]);
  const float4 bb = ld4(&bv2[v*1024 + d]);
  const float4 f  = ld4(&feat[base+d]);
  float4 img;
  img.x = 0.6f*fmaxf(y.x+bb.x,0.f) + 0.4f*f.x;
  img.y = 0.6f*fmaxf(y.y+bb.y,0.f) + 0.4f*f.y;
  img.z = 0.6f*fmaxf(y.z+bb.z,0.f) + 0.4f*f.z;
  img.w = 0.6f*fmaxf(y.w+bb.w,0.f) + 0.4f*f.w;
  const float ss = img.x*img.x + img.y*img.y + img.z*img.z + img.w*img.w;
  const float rn = rsqrtf(blockSum256(ss, sh4));
  uint2 o; o.x = pk(img.x*rn, img.y*rn); o.y = pk(img.z*rn, img.w*rn);
  *reinterpret_cast<uint2*>(&outp[base+d]) = o;
}

// ------------------------------ Sinkhorn -----------------------------------
// Single kernel; sim comes as 2 split-K slabs (stride 2621440 fp32) summed on
// load. Each thread owns one (b,c) 10x4 OT problem; iterates to LOCAL wave
// convergence (wave-sum |dr| <= 0.25); emits logits.
__global__ __launch_bounds__(256)
void sinkhorn_solve(const float* __restrict__ sim, const float* __restrict__ lsp,
                    float* __restrict__ out)
{
  const int n = blockIdx.x*256 + threadIdx.x;     // 0..51199
  const int b = n / 100, c = n % 100;
  float S[10][4], Km[10][4];
  #pragma unroll
  for (int v=0; v<10; ++v){
    const long off = (long)(b*10+v)*512 + c*4;
    const float4 a0 = ld4(&sim[off]);
    const float4 a1 = ld4(&sim[2621440L + off]);
    S[v][0]=a0.x+a1.x; S[v][1]=a0.y+a1.y; S[v][2]=a0.z+a1.z; S[v][3]=a0.w+a1.w;
    #pragma unroll
    for (int p=0;p<4;++p) Km[v][p] = expf((S[v][p]-1.f)*100.f);
  }
  float r[10], cc[4];
  #pragma unroll
  for (int v=0;v<10;++v) r[v]=1.f;
  #pragma unroll
  for (int p=0;p<4;++p) cc[p]=1.f;
  for (int j=0; j<1000; ++j){
    float lerr = 0.f;
    #pragma unroll
    for (int v=0;v<10;++v){
      const float s = Km[v][0]*cc[0]+Km[v][1]*cc[1]+Km[v][2]*cc[2]+Km[v][3]*cc[3];
      const float rn = __fdividef(0.1f, s);
      lerr += fabsf(rn - r[v]); r[v]=rn;
    }
    #pragma unroll
    for (int p=0;p<4;++p){
      float s = 0.f;
      #pragma unroll
      for (int v=0;v<10;++v) s += Km[v][p]*r[v];
      cc[p] = __fdividef(0.25f, s);
    }
    float w = lerr;
    #pragma unroll
    for (int m=32; m; m>>=1) w += __shfl_xor(w, m, 64);
    if (w <= 0.25f) break;            // uniform across the wave
  }
  float dOT = 0.f;
  #pragma unroll
  for (int v=0;v<10;++v)
    #pragma unroll
    for (int p=0;p<4;++p)
      dOT += r[v]*Km[v][p]*cc[p]*(1.f - S[v][p]);
  out[n] = expf(lsp[0]) * (1.f - dOT);
}

// ---------------------------------------------------------------------------
extern "C" void kernel_launch(void* const* d_in, const int* in_sizes, int n_in,
                              void* d_out, int out_size, void* d_ws, size_t ws_size,
                              hipStream_t stream)
{
  const float* feat  = (const float*)d_in[0];
  const float* textf = (const float*)d_in[1];
  const float* fr    = (const float*)d_in[2];
  const float* bn1g  = (const float*)d_in[3];
  const float* bn1b  = (const float*)d_in[4];
  const float* Wg    = (const float*)d_in[5];
  const float* bg    = (const float*)d_in[6];
  const float* bn2g  = (const float*)d_in[7];
  const float* bn2b  = (const float*)d_in[8];
  const float* Wv1   = (const float*)d_in[9];
  const float* bv1   = (const float*)d_in[10];
  const float* Wv2   = (const float*)d_in[11];
  const float* bv2   = (const float*)d_in[12];
  const float* ls    = (const float*)d_in[13];
  float* out = (float*)d_out;
  char* base = (char*)d_ws;

  // workspace layout (bytes); regions reused over time:
  u16*   Xb  = (u16*)(base + 20971520);   // 10.49MB: xbn_bf16, later img_bf16
  float* P   = (float*)(base + 31457280); // 33.55MB: colstats slabs / split-K / y3 / sim
  float* P2  = P + 1310720;               // stage-2 slab area (within P region)
  float* y1  = (float*)(base + 67108864); // 2.10MB
  u16*   Gb  = (u16*)(base + 69206016);   // 1.05MB
  u16*   Hb  = (u16*)(base + 70254592);   // 1.05MB
  u16*   Tb  = (u16*)(base + 71303168);   // 1.05MB (512x1024, rows 400+ zero)
  float* ex  = (float*)(base + 72351744); // stats
  float* bn1st=ex, *bn2st=ex+2048;        // each 2048: sum||sq

  // --- BN1 + fusion scale -> xbn bf16 (stats via 3-stage slab tree in P) ---
  colstats_p1<<<640,256,0,stream>>>(feat, 8, fr, P);
  colstats_reduce<<<dim3(8,20),256,0,stream>>>(P, P2, 640, 32);
  colstats_reduce<<<dim3(8,1),256,0,stream>>>(P2, bn1st, 20, 20);
  bn_apply_bf16<<<5120,256,0,stream>>>(feat, fr, bn1st, 1.f/5120.f,
                                       bn1g, bn1b, 0, Xb);

  // --- GEMM1: y1 = xbn @ Wg^T  (512x1024x10240), split-K 16, 1024 blocks ---
  gemm_bf32b_nt<<<dim3(8,8,16),256,0,stream>>>(Xb, Wg, P, 10240,10240,1024, 640, 524288L);
  reduce_f32<<<512,256,0,stream>>>(P, 16, 524288, bg, y1);

  // --- BN2 + relu -> g bf16 ---
  colstats_p1<<<128,256,0,stream>>>(y1, 4, nullptr, P);
  colstats_reduce<<<dim3(8,8),256,0,stream>>>(P, P2, 128, 16);
  colstats_reduce<<<dim3(8,1),256,0,stream>>>(P2, bn2st, 8, 8);
  bn_apply_bf16<<<512,256,0,stream>>>(y1, nullptr, bn2st, 1.f/512.f,
                                      bn2g, bn2b, 1, Gb);

  // --- GEMM2: h = relu(g @ Wv1^T + bv1)  (512x1024x1024), split-K 16 ---
  gemm_bf32b_nt<<<dim3(8,8,16),256,0,stream>>>(Gb, Wv1, P, 1024,1024,1024, 64, 524288L);
  reduce_bf16<<<512,256,0,stream>>>(P, 16, 524288, bv1, Hb);

  // --- GEMM3: y3 = h @ Wv2^T  (512x10240x1024), 640 blocks ---
  gemm_bf32b_nt<<<dim3(80,8,1),256,0,stream>>>(Hb, Wv2, P, 1024,1024,10240, 1024, 0L);
  mix_norm_bf16<<<5120,256,0,stream>>>(P, feat, bv2, Xb);

  // --- text norm + sim (5120x512x1024), split-K 2, 640 blocks ---
  rownorm_bf16<<<512,256,0,stream>>>(textf, Tb);
  gemm_bf16_nt<<<dim3(4,80,2),256,0,stream>>>(Xb, Tb, P, 1024,1024,512, 512, 2621440L);

  // --- Sinkhorn + logits (single kernel; sums the 2 sim slabs) ---
  sinkhorn_solve<<<200,256,0,stream>>>(P, ls, out);
}

// Round 9
// 152.785 us; speedup vs baseline: 1.1300x; 1.1300x over previous
//
#include <hip/hip_runtime.h>
#include <cstdint>

// ---------------------------------------------------------------------------
// PointCLIP forward on MI355X. GEMMs in bf16 MFMA (fp32 accum), rest fp32.
// Weights pre-converted to bf16 once (B-traffic halved); split-K GEMM blocks
// mapped so each XCD's K-slab working set fits its private 4MB L2.
// Dims fixed per reference: B=512, V=10, D=1024, C=100, P=4.
// ---------------------------------------------------------------------------

typedef unsigned short u16;
typedef __attribute__((ext_vector_type(8))) short bf8v;   // 8 bf16 (4 VGPR)
typedef __attribute__((ext_vector_type(4))) float f4v;    // 4 f32 acc

__device__ __forceinline__ float4 ld4(const float* p){ return *reinterpret_cast<const float4*>(p); }
__device__ __forceinline__ void st4(float* p, float4 v){ *reinterpret_cast<float4*>(p) = v; }
__device__ __forceinline__ u16 f2bf(float x){            // RNE fp32 -> bf16
  uint32_t u = __float_as_uint(x);
  return (u16)((u + 0x7FFFu + ((u>>16)&1u)) >> 16);
}
__device__ __forceinline__ uint32_t pk(float a, float b){
  return (uint32_t)f2bf(a) | ((uint32_t)f2bf(b)<<16);
}
__device__ __forceinline__ void glds16(const u16* g, u16* l){
  __builtin_amdgcn_global_load_lds(
      (const __attribute__((address_space(1))) unsigned int*)g,
      (__attribute__((address_space(3))) unsigned int*)l, 16, 0, 0);
}

// ---------------- bf16 NT MFMA GEMM, 64x128 tile ---------------------------
// A: (M,K) bf16 row-major. B: (N,K) bf16 row-major. C fp32 ldc, split-K slab.
// 4 waves; wave w owns 32x64. BK=32, XOR slot-swizzle, LDS double-buffer.
// map: 0 = plain 3D grid (bx,by,bz from blockIdx)
//      1 = z-affinity 1D: xcd=blk%8 owns contiguous K-slabs (slab WS in L2)
//      2 = n-affinity 1D: xcd=blk%8 owns an N-chunk of B (chunk in L2)
__global__ __launch_bounds__(256,4)
void gemm_bf16_nt(const u16* __restrict__ A, const u16* __restrict__ B,
                  float* __restrict__ C, int lda, int ldb, int ldc,
                  int kLen, long strideCz, int map, int NBX, int NBY)
{
  __shared__ u16 As0[2048], Bs0[4096], As1[2048], Bs1[4096];
  const int tid = threadIdx.x, lane = tid & 63, w = tid >> 6;

  int bx, by, bz;
  if (map == 0){ bx = blockIdx.x; by = blockIdx.y; bz = blockIdx.z; }
  else {
    const int i = blockIdx.x, xcd = i & 7, j = i >> 3;
    if (map == 1){
      const int mnC = NBX*NBY;
      const int zPer = (gridDim.x >> 3) / mnC;
      bz = xcd*zPer + j/mnC;
      const int mn = j % mnC; bx = mn % NBX; by = mn / NBX;
    } else {
      const int nbxPer = NBX >> 3;
      bx = xcd*nbxPer + j % nbxPer; by = j / nbxPer; bz = 0;
    }
  }

  const long bm = (long)by*64, bn = (long)bx*128;
  const long kz = (long)bz*kLen;
  C += (long)bz*strideCz;

  const int srow  = lane>>2;
  const int sslot = (lane&3) ^ ((lane>>3)&3);
  const u16* Ag = A + (bm + w*16 + srow)*(long)lda + kz + sslot*8;
  const u16* Bg = B + (bn + w*32 + srow)*(long)ldb + kz + sslot*8;
  const long b16 = 16L*ldb;
  const int woffA = w*512, woffB = w*1024;

  const int fr = lane & 15;
  const int rslot = ((lane>>4) ^ ((lane>>1)&3))*16;
  const int wr = (w>>1)*32, wc = (w&1)*64;

  const f4v zero = {0.f,0.f,0.f,0.f};
  f4v acc[2][4];
  #pragma unroll
  for (int i2=0;i2<2;i2++)
    #pragma unroll
    for (int j2=0;j2<4;j2++) acc[i2][j2]=zero;

  auto STAGE = [&](u16* Al, u16* Bl, int kt){
    glds16(Ag + kt,       Al + woffA);
    glds16(Bg + kt,       Bl + woffB);
    glds16(Bg + kt + b16, Bl + woffB + 512);
  };
  auto COMPUTE = [&](const u16* Asb, const u16* Bsb){
    bf8v af[2], bf[4];
    #pragma unroll
    for (int mi=0; mi<2; ++mi)
      af[mi] = *(const bf8v*)((const char*)Asb + (wr+mi*16+fr)*64 + rslot);
    #pragma unroll
    for (int nj=0; nj<4; ++nj)
      bf[nj] = *(const bf8v*)((const char*)Bsb + (wc+nj*16+fr)*64 + rslot);
    #pragma unroll
    for (int mi=0; mi<2; ++mi)
      #pragma unroll
      for (int nj=0; nj<4; ++nj)
        acc[mi][nj] = __builtin_amdgcn_mfma_f32_16x16x32_bf16(af[mi], bf[nj], acc[mi][nj], 0,0,0);
  };

  STAGE(As0, Bs0, 0);
  __syncthreads();
  int kt = 32;
  for (; kt < kLen - 32; kt += 64){
    STAGE(As1, Bs1, kt);
    COMPUTE(As0, Bs0);
    __syncthreads();
    STAGE(As0, Bs0, kt + 32);
    COMPUTE(As1, Bs1);
    __syncthreads();
  }
  STAGE(As1, Bs1, kt);
  COMPUTE(As0, Bs0);
  __syncthreads();
  COMPUTE(As1, Bs1);

  const int orow = (lane>>4)*4;
  #pragma unroll
  for (int mi=0;mi<2;++mi){
    #pragma unroll
    for (int q=0;q<4;++q){
      const long row = bm + wr + mi*16 + orow + q;
      float* Crow = C + row*(long)ldc + bn + wc + fr;
      #pragma unroll
      for (int nj=0;nj<4;++nj) Crow[nj*16] = acc[mi][nj][q];
    }
  }
}

// --------------------- fp32 -> bf16 convert (weights) ----------------------
__global__ __launch_bounds__(256)
void cvt_bf16(const float* __restrict__ in, u16* __restrict__ out, long n8)
{
  for (long i = (long)blockIdx.x*256 + threadIdx.x; i < n8; i += (long)gridDim.x*256){
    const float4 a = ld4(&in[i*8]), b = ld4(&in[i*8+4]);
    uint4 o;
    o.x = pk(a.x,a.y); o.y = pk(a.z,a.w);
    o.z = pk(b.x,b.y); o.w = pk(b.z,b.w);
    *reinterpret_cast<uint4*>(&out[i*8]) = o;
  }
}

// --------------------- split-K reduce variants -----------------------------
__global__ __launch_bounds__(256)
void reduce_f32(const float* __restrict__ P, int S, int MN,
                const float* __restrict__ bias, float* __restrict__ out)
{
  const long i = ((long)blockIdx.x*256 + threadIdx.x)*4;
  float4 s = ld4(&P[i]);
  for (int z=1; z<S; ++z){
    const float4 v = ld4(&P[(long)z*MN + i]);
    s.x+=v.x; s.y+=v.y; s.z+=v.z; s.w+=v.w;
  }
  const float4 b = ld4(&bias[(int)(i & 1023)]);
  s.x+=b.x; s.y+=b.y; s.z+=b.z; s.w+=b.w;
  st4(&out[i], s);
}

__global__ __launch_bounds__(256)
void reduce_bf16(const float* __restrict__ P, int S, int MN,
                 const float* __restrict__ bias, u16* __restrict__ out)
{
  const long i = ((long)blockIdx.x*256 + threadIdx.x)*4;
  float4 s = ld4(&P[i]);
  for (int z=1; z<S; ++z){
    const float4 v = ld4(&P[(long)z*MN + i]);
    s.x+=v.x; s.y+=v.y; s.z+=v.z; s.w+=v.w;
  }
  const float4 b = ld4(&bias[(int)(i & 1023)]);
  s.x = fmaxf(s.x+b.x,0.f); s.y = fmaxf(s.y+b.y,0.f);
  s.z = fmaxf(s.z+b.z,0.f); s.w = fmaxf(s.w+b.w,0.f);
  uint2 o; o.x = pk(s.x,s.y); o.y = pk(s.z,s.w);
  *reinterpret_cast<uint2*>(&out[i]) = o;
}

// --------------- column stats: multi-stage tree, NO atomics ----------------
__global__ __launch_bounds__(256)
void colstats_p1(const float* __restrict__ X, int rpb, const float* __restrict__ fr,
                 float* __restrict__ part)
{
  const int c = threadIdx.x*4;
  const long r0 = (long)blockIdx.x*rpb;
  float4 s = make_float4(0,0,0,0), q = make_float4(0,0,0,0);
  for (int rr=0; rr<rpb; ++rr){
    const long r = r0+rr;
    float4 x = ld4(&X[r*1024 + c]);
    if (fr){ const float f = fr[(int)(r%10)]; x.x*=f; x.y*=f; x.z*=f; x.w*=f; }
    s.x+=x.x; s.y+=x.y; s.z+=x.z; s.w+=x.w;
    q.x+=x.x*x.x; q.y+=x.y*x.y; q.z+=x.z*x.z; q.w+=x.w*x.w;
  }
  float* p = part + (long)blockIdx.x*2048;
  st4(&p[c], s);
  st4(&p[1024+c], q);
}

__global__ __launch_bounds__(256)
void colstats_reduce(const float* __restrict__ in, float* __restrict__ out,
                     int nslab, int chunk)
{
  const int idx = blockIdx.x*256 + threadIdx.x;    // 0..2047
  const int s0 = blockIdx.y*chunk;
  const int s1 = min(nslab, s0+chunk);
  float a0=0.f, a1=0.f, a2=0.f, a3=0.f;
  int s = s0;
  for (; s+4 <= s1; s += 4){
    a0 += in[(long)s*2048+idx];
    a1 += in[(long)(s+1)*2048+idx];
    a2 += in[(long)(s+2)*2048+idx];
    a3 += in[(long)(s+3)*2048+idx];
  }
  for (; s < s1; ++s) a0 += in[(long)s*2048+idx];
  out[(long)blockIdx.y*2048 + idx] = (a0+a1)+(a2+a3);
}

// BN apply with inline finalize (same arithmetic as reference BN).
__global__ __launch_bounds__(256)
void bn_apply_bf16(const float* __restrict__ X, const float* __restrict__ fr,
                   const float* __restrict__ stats, float invN,
                   const float* __restrict__ gamma,
                   const float* __restrict__ beta, int relu, u16* __restrict__ out)
{
  const long i = ((long)blockIdx.x*256 + threadIdx.x)*4;
  const int d = (int)(i & 1023);
  const float4 s  = ld4(&stats[d]);
  const float4 qq = ld4(&stats[1024+d]);
  const float4 gm = ld4(&gamma[d]);
  const float4 bt = ld4(&beta[d]);
  float4 sc, sh;
  { const float m=s.x*invN, v=qq.x*invN-m*m; sc.x=gm.x*rsqrtf(v+1e-5f); sh.x=bt.x-m*sc.x; }
  { const float m=s.y*invN, v=qq.y*invN-m*m; sc.y=gm.y*rsqrtf(v+1e-5f); sh.y=bt.y-m*sc.y; }
  { const float m=s.z*invN, v=qq.z*invN-m*m; sc.z=gm.z*rsqrtf(v+1e-5f); sh.z=bt.z-m*sc.z; }
  { const float m=s.w*invN, v=qq.w*invN-m*m; sc.w=gm.w*rsqrtf(v+1e-5f); sh.w=bt.w-m*sc.w; }
  float4 x = ld4(&X[i]);
  if (fr){ const float f = fr[(int)((i>>10)%10)]; x.x*=f; x.y*=f; x.z*=f; x.w*=f; }
  x.x = x.x*sc.x + sh.x; x.y = x.y*sc.y + sh.y;
  x.z = x.z*sc.z + sh.z; x.w = x.w*sc.w + sh.w;
  if (relu){ x.x=fmaxf(x.x,0.f); x.y=fmaxf(x.y,0.f); x.z=fmaxf(x.z,0.f); x.w=fmaxf(x.w,0.f); }
  uint2 o; o.x = pk(x.x,x.y); o.y = pk(x.z,x.w);
  *reinterpret_cast<uint2*>(&out[i]) = o;
}

__device__ __forceinline__ float blockSum256(float v, float* sh4){
  #pragma unroll
  for (int m=32; m; m>>=1) v += __shfl_xor(v, m, 64);
  const int w = threadIdx.x >> 6;
  if ((threadIdx.x & 63) == 0) sh4[w] = v;
  __syncthreads();
  return sh4[0]+sh4[1]+sh4[2]+sh4[3];
}

// text rows L2-normalized -> bf16; rows [400,512) zero-padded.
__global__ __launch_bounds__(256)
void rownorm_bf16(const float* __restrict__ X, u16* __restrict__ out)
{
  __shared__ float sh4[4];
  const int row = blockIdx.x;
  const int d = threadIdx.x*4;
  if (row >= 400){ *reinterpret_cast<uint2*>(&out[(long)row*1024 + d]) = make_uint2(0,0); return; }
  const long base = (long)row*1024 + d;
  const float4 x = ld4(&X[base]);
  const float ss = x.x*x.x + x.y*x.y + x.z*x.z + x.w*x.w;
  const float rn = rsqrtf(blockSum256(ss, sh4));
  uint2 o; o.x = pk(x.x*rn, x.y*rn); o.y = pk(x.z*rn, x.w*rn);
  *reinterpret_cast<uint2*>(&out[base]) = o;
}

// img = 0.6*relu(y3+bv2) + 0.4*feat; L2-normalize per (b,v) row; bf16 out.
__global__ __launch_bounds__(256)
void mix_norm_bf16(const float* __restrict__ P, const float* __restrict__ feat,
                   const float* __restrict__ bv2, u16* __restrict__ outp)
{
  __shared__ float sh4[4];
  const int m = blockIdx.x;            // 0..5119 = b*10+v
  const int v = m % 10;
  const long base = (long)m*1024;
  const int d = threadIdx.x*4;
  const float4 y  = ld4(&P[base+d]);
  const float4 bb = ld4(&bv2[v*1024 + d]);
  const float4 f  = ld4(&feat[base+d]);
  float4 img;
  img.x = 0.6f*fmaxf(y.x+bb.x,0.f) + 0.4f*f.x;
  img.y = 0.6f*fmaxf(y.y+bb.y,0.f) + 0.4f*f.y;
  img.z = 0.6f*fmaxf(y.z+bb.z,0.f) + 0.4f*f.z;
  img.w = 0.6f*fmaxf(y.w+bb.w,0.f) + 0.4f*f.w;
  const float ss = img.x*img.x + img.y*img.y + img.z*img.z + img.w*img.w;
  const float rn = rsqrtf(blockSum256(ss, sh4));
  uint2 o; o.x = pk(img.x*rn, img.y*rn); o.y = pk(img.z*rn, img.w*rn);
  *reinterpret_cast<uint2*>(&outp[base+d]) = o;
}

// ------------------------------ Sinkhorn -----------------------------------
// Single kernel; sim comes as 2 split-K slabs (stride 2621440 fp32) summed on
// load. Each thread owns one (b,c) 10x4 OT problem; iterates to LOCAL wave
// convergence (wave-sum |dr| <= 0.25); emits logits.
__global__ __launch_bounds__(256)
void sinkhorn_solve(const float* __restrict__ sim, const float* __restrict__ lsp,
                    float* __restrict__ out)
{
  const int n = blockIdx.x*256 + threadIdx.x;     // 0..51199
  const int b = n / 100, c = n % 100;
  float S[10][4], Km[10][4];
  #pragma unroll
  for (int v=0; v<10; ++v){
    const long off = (long)(b*10+v)*512 + c*4;
    const float4 a0 = ld4(&sim[off]);
    const float4 a1 = ld4(&sim[2621440L + off]);
    S[v][0]=a0.x+a1.x; S[v][1]=a0.y+a1.y; S[v][2]=a0.z+a1.z; S[v][3]=a0.w+a1.w;
    #pragma unroll
    for (int p=0;p<4;++p) Km[v][p] = expf((S[v][p]-1.f)*100.f);
  }
  float r[10], cc[4];
  #pragma unroll
  for (int v=0;v<10;++v) r[v]=1.f;
  #pragma unroll
  for (int p=0;p<4;++p) cc[p]=1.f;
  for (int j=0; j<1000; ++j){
    float lerr = 0.f;
    #pragma unroll
    for (int v=0;v<10;++v){
      const float s = Km[v][0]*cc[0]+Km[v][1]*cc[1]+Km[v][2]*cc[2]+Km[v][3]*cc[3];
      const float rn = __fdividef(0.1f, s);
      lerr += fabsf(rn - r[v]); r[v]=rn;
    }
    #pragma unroll
    for (int p=0;p<4;++p){
      float s = 0.f;
      #pragma unroll
      for (int v=0;v<10;++v) s += Km[v][p]*r[v];
      cc[p] = __fdividef(0.25f, s);
    }
    float w = lerr;
    #pragma unroll
    for (int m=32; m; m>>=1) w += __shfl_xor(w, m, 64);
    if (w <= 0.25f) break;            // uniform across the wave
  }
  float dOT = 0.f;
  #pragma unroll
  for (int v=0;v<10;++v)
    #pragma unroll
    for (int p=0;p<4;++p)
      dOT += r[v]*Km[v][p]*cc[p]*(1.f - S[v][p]);
  out[n] = expf(lsp[0]) * (1.f - dOT);
}

// ---------------------------------------------------------------------------
extern "C" void kernel_launch(void* const* d_in, const int* in_sizes, int n_in,
                              void* d_out, int out_size, void* d_ws, size_t ws_size,
                              hipStream_t stream)
{
  const float* feat  = (const float*)d_in[0];
  const float* textf = (const float*)d_in[1];
  const float* fr    = (const float*)d_in[2];
  const float* bn1g  = (const float*)d_in[3];
  const float* bn1b  = (const float*)d_in[4];
  const float* Wg    = (const float*)d_in[5];
  const float* bg    = (const float*)d_in[6];
  const float* bn2g  = (const float*)d_in[7];
  const float* bn2b  = (const float*)d_in[8];
  const float* Wv1   = (const float*)d_in[9];
  const float* bv1   = (const float*)d_in[10];
  const float* Wv2   = (const float*)d_in[11];
  const float* bv2   = (const float*)d_in[12];
  const float* ls    = (const float*)d_in[13];
  float* out = (float*)d_out;
  char* base = (char*)d_ws;

  // workspace layout (bytes); regions reused over time (total ~72.4MB):
  u16*   WB  = (u16*)(base + 0);          // 20.97MB: Wg_bf16, then Wv2_bf16
  u16*   Xb  = (u16*)(base + 20971520);   // 10.49MB: xbn_bf16, later img_bf16
  float* P   = (float*)(base + 31457280); // 33.55MB: colstats slabs / split-K / y3 / sim
  float* P2  = P + 1310720;               // stage-2 slab area (within P region)
  u16*   W1b = (u16*)(base + 65011712);   // 2.10MB: Wv1_bf16
  float* y1  = (float*)(base + 67108864); // 2.10MB
  u16*   Gb  = (u16*)(base + 69206016);   // 1.05MB
  u16*   Hb  = (u16*)(base + 70254592);   // 1.05MB
  u16*   Tb  = (u16*)(base + 71303168);   // 1.05MB (512x1024, rows 400+ zero)
  float* ex  = (float*)(base + 72351744); // stats
  float* bn1st=ex, *bn2st=ex+2048;        // each 2048: sum||sq

  // --- Wg -> bf16 (one-time; B-traffic in GEMM1 halves and L2-fits) ---
  cvt_bf16<<<2048,256,0,stream>>>(Wg, WB, 1310720);

  // --- BN1 + fusion scale -> xbn bf16 (stats via 3-stage slab tree in P) ---
  colstats_p1<<<640,256,0,stream>>>(feat, 8, fr, P);
  colstats_reduce<<<dim3(8,20),256,0,stream>>>(P, P2, 640, 32);
  colstats_reduce<<<dim3(8,1),256,0,stream>>>(P2, bn1st, 20, 20);
  bn_apply_bf16<<<5120,256,0,stream>>>(feat, fr, bn1st, 1.f/5120.f,
                                       bn1g, bn1b, 0, Xb);

  // --- GEMM1: y1 = xbn @ Wg^T (512x1024x10240), splitK16, z-affinity ---
  // 1024 blocks; XCD x owns z in {2x,2x+1}; slab WS (0.64+1.28MB)*2 < 4MB L2.
  gemm_bf16_nt<<<1024,256,0,stream>>>(Xb, WB, P, 10240,10240,1024, 640, 524288L,
                                      1, 8, 8);
  reduce_f32<<<512,256,0,stream>>>(P, 16, 524288, bg, y1);

  // --- BN2 + relu -> g bf16; Wv1 -> bf16 ---
  colstats_p1<<<128,256,0,stream>>>(y1, 4, nullptr, P);
  colstats_reduce<<<dim3(8,8),256,0,stream>>>(P, P2, 128, 16);
  colstats_reduce<<<dim3(8,1),256,0,stream>>>(P2, bn2st, 8, 8);
  bn_apply_bf16<<<512,256,0,stream>>>(y1, nullptr, bn2st, 1.f/512.f,
                                      bn2g, bn2b, 1, Gb);
  cvt_bf16<<<512,256,0,stream>>>(Wv1, W1b, 131072);

  // --- GEMM2: h = relu(g @ Wv1^T + bv1) (512x1024x1024), splitK8, z-aff ---
  gemm_bf16_nt<<<512,256,0,stream>>>(Gb, W1b, P, 1024,1024,1024, 128, 524288L,
                                     1, 8, 8);
  reduce_bf16<<<512,256,0,stream>>>(P, 8, 524288, bv1, Hb);

  // --- Wv2 -> bf16 (reuses WB; Wg no longer needed) ---
  cvt_bf16<<<2048,256,0,stream>>>(Wv2, WB, 1310720);

  // --- GEMM3: y3 = h @ Wv2^T (512x10240x1024), n-affinity (2.6MB B/XCD) ---
  gemm_bf16_nt<<<640,256,0,stream>>>(Hb, WB, P, 1024,1024,10240, 1024, 0L,
                                     2, 80, 8);
  mix_norm_bf16<<<5120,256,0,stream>>>(P, feat, bv2, Xb);

  // --- text norm + sim (5120x512x1024), split-K 2 ---
  rownorm_bf16<<<512,256,0,stream>>>(textf, Tb);
  gemm_bf16_nt<<<dim3(4,80,2),256,0,stream>>>(Xb, Tb, P, 1024,1024,512, 512,
                                              2621440L, 0, 0, 0);

  // --- Sinkhorn + logits (single kernel; sums the 2 sim slabs) ---
  sinkhorn_solve<<<200,256,0,stream>>>(P, ls, out);
}